// Round 5
// baseline (763.466 us; speedup 1.0000x reference)
//
#include <hip/hip_runtime.h>

#define Bn 8
#define Vn 3
#define Hn 512
#define Wn 640
#define Nn (Hn * Wn)
#define PX 16                     // pixels per thread (16 divides 640: no row wrap)
#define TPB 256
#define XBLKS (Nn / (TPB * PX))   // 80
#define GRIDN (XBLKS * Vn * Bn)   // 1920 blocks

struct __attribute__((aligned(4))) fpair { float a, b; };

__device__ __forceinline__ float rfl(float x) {
    return __int_as_float(__builtin_amdgcn_readfirstlane(__float_as_int(x)));
}

// Inline P = K * RT_j * inv(RT_i) * inv(K), rows 0..2, analytic affine inverses.
// Bottom row of P is exactly [0,0,0,1]. Validated: absmax 0.0 vs reference.
__device__ __forceinline__ void computeQ(const float* __restrict__ K,
                                         const float* __restrict__ RT,
                                         int b, int i, float Q[Vn][12]) {
    const float* Kb = K + (size_t)b * 16;
    const float f  = Kb[0], cx = Kb[2], cy = Kb[6];
    const float rf = 1.0f / f;
    const float* Ti = RT + (size_t)(b * Vn + i) * 16;
    const float A00=Ti[0], A01=Ti[1], A02=Ti[2],  A03=Ti[3];
    const float A10=Ti[4], A11=Ti[5], A12=Ti[6],  A13=Ti[7];
    const float A20=Ti[8], A21=Ti[9], A22=Ti[10], A23=Ti[11];
    const float I00=A00, I01=A10, I02=A20, I03=-(A00*A03 + A10*A13 + A20*A23);
    const float I10=A01, I11=A11, I12=A21, I13=-(A01*A03 + A11*A13 + A21*A23);
    const float I20=A02, I21=A12, I22=A22, I23=-(A02*A03 + A12*A13 + A22*A23);
    #pragma unroll
    for (int j = 0; j < Vn; ++j) {
        const float* Tj = RT + (size_t)(b * Vn + j) * 16;
        const float B00=Tj[0], B01=Tj[1], B02=Tj[2],  B03=Tj[3];
        const float B10=Tj[4], B11=Tj[5], B12=Tj[6],  B13=Tj[7];
        const float B20=Tj[8], B21=Tj[9], B22=Tj[10], B23=Tj[11];
        const float M00=B00*I00+B01*I10+B02*I20, M01=B00*I01+B01*I11+B02*I21,
                    M02=B00*I02+B01*I12+B02*I22, M03=B00*I03+B01*I13+B02*I23+B03;
        const float M10=B10*I00+B11*I10+B12*I20, M11=B10*I01+B11*I11+B12*I21,
                    M12=B10*I02+B11*I12+B12*I22, M13=B10*I03+B11*I13+B12*I23+B13;
        const float M20=B20*I00+B21*I10+B22*I20, M21=B20*I01+B21*I11+B22*I21,
                    M22=B20*I02+B21*I12+B22*I22, M23=B20*I03+B21*I13+B22*I23+B23;
        const float G00=f*M00+cx*M20, G01=f*M01+cx*M21, G02=f*M02+cx*M22, G03=f*M03+cx*M23;
        const float G10=f*M10+cy*M20, G11=f*M11+cy*M21, G12=f*M12+cy*M22, G13=f*M13+cy*M23;
        const float G20=M20,          G21=M21,          G22=M22,          G23=M23;
        Q[j][0]  = rfl(G00*rf);  Q[j][1]  = rfl(G01*rf);
        Q[j][2]  = rfl(G02 - (cx*rf)*G00 - (cy*rf)*G01);  Q[j][3]  = rfl(G03);
        Q[j][4]  = rfl(G10*rf);  Q[j][5]  = rfl(G11*rf);
        Q[j][6]  = rfl(G12 - (cx*rf)*G10 - (cy*rf)*G11);  Q[j][7]  = rfl(G13);
        Q[j][8]  = rfl(G20*rf);  Q[j][9]  = rfl(G21*rf);
        Q[j][10] = rfl(G22 - (cx*rf)*G20 - (cy*rf)*G21);  Q[j][11] = rfl(G23);
    }
}

// Pipeline state for one pixel x one source view j.
// wA/wB encode the border corner-swap as a WEIGHT swap (proof in R24 notes):
//   interior: (wA,wB) = (wx0v,wx1v) -> fmaf(wx0,q.a, wx1*q.b) == old fast path
//   x-border: (wA,wB) = (wx1v,wx0v) -> exactly the old masked path's routing.
// m = inb ? 1.0 : 0.0 kills OOB contributions exactly (all image values > 0,
// weights in [0,1] -> no -0/NaN hazards; 1.0f*x is bitwise x).
struct JState {
    float q0a, q0b, q1a, q1b;
    float wA, wB, wy0v, wy1v;
    float Z, m;
};

// ---------- Main: R25 manual 1-deep software pipeline ----------
// R24 post-mortem: compiler won't pipeline loads across exec-masked branchy
// bodies (ballot fast path). VALU issue (~52K cy/CU) and TCP lane-request
// processing (~52K cy/CU) run in SUM -> 103K cy = 43 us. This version splits
// each pixel into A (projection+weights+masked loads -> registers) and B
// (pure-FMA consume, zero branches/cmps), double-buffered so A(k+1)'s 6 loads
// are in flight while B(k) consumes A(k)'s -> counted vmcnt waits, pipes
// overlap. Per-sample math bitwise identical; accumulation order unchanged.
__global__ __launch_bounds__(TPB, 6) void loss_main_kernel(const float* __restrict__ pred,
                                                           const float* __restrict__ K,
                                                           const float* __restrict__ RT,
                                                           float* __restrict__ part) {
    // b = blockIdx.x % 8: XCD-batch L2 locality (one batch's 3 planes = 3.93 MB).
    const int id   = blockIdx.x;
    const int b    = id & 7;
    const int r    = id >> 3;
    const int i    = r % Vn;
    const int xblk = r / Vn;           // 0..79

    float Q[Vn][12];
    computeQ(K, RT, b, i, Q);

    // R20 balance bijection over the 512x40 segment grid (kept):
    const int tid  = threadIdx.x;
    const int h    = (xblk >= 40) ? 1 : 0;
    const int c0   = xblk - 40 * h;
    const int yrow = 2 * tid + h;
    int c = c0 + tid;
    c -= (c / 40) * 40;
    const int xcol = c << 4;
    const int base = yrow * Wn + xcol;
    const float fy = (float)yrow;

    const float* dptr = pred + (size_t)(b * Vn + i) * Nn + base;
    float dv[PX];
    {
        const float4 a0 = *reinterpret_cast<const float4*>(dptr);
        const float4 a1 = *reinterpret_cast<const float4*>(dptr + 4);
        const float4 a2 = *reinterpret_cast<const float4*>(dptr + 8);
        const float4 a3 = *reinterpret_cast<const float4*>(dptr + 12);
        dv[0]=a0.x; dv[1]=a0.y; dv[2]=a0.z; dv[3]=a0.w;
        dv[4]=a1.x; dv[5]=a1.y; dv[6]=a1.z; dv[7]=a1.w;
        dv[8]=a2.x; dv[9]=a2.y; dv[10]=a2.z; dv[11]=a2.w;
        dv[12]=a3.x; dv[13]=a3.y; dv[14]=a3.z; dv[15]=a3.w;
    }

    const float cW = (float)Wn / (float)(Wn - 1);   // ix = X*cW - 0.5
    const float cH = (float)Hn / (float)(Hn - 1);

    float num[Vn] = {0.0f, 0.0f, 0.0f};
    float den[Vn] = {0.0f, 0.0f, 0.0f};

    float rx[Vn], ry[Vn], rz[Vn];
    #pragma unroll
    for (int j = 0; j < Vn; ++j) {
        rx[j] = fmaf(Q[j][1], fy, Q[j][2]);
        ry[j] = fmaf(Q[j][5], fy, Q[j][6]);
        rz[j] = fmaf(Q[j][9], fy, Q[j][10]);
    }

    const float* __restrict__ img0 = pred + (size_t)(b * Vn + 0) * Nn;
    const float* __restrict__ img1 = pred + (size_t)(b * Vn + 1) * Nn;
    const float* __restrict__ img2 = pred + (size_t)(b * Vn + 2) * Nn;

    // Double-buffered pipeline state, all statically indexed (k compile-time
    // in the fully unrolled loop) -> stays in registers (rule #20).
    JState st[2][Vn];
    #pragma unroll
    for (int s = 0; s < 2; ++s)
        #pragma unroll
        for (int j = 0; j < Vn; ++j) {
            st[s][j].q0a = 0.0f; st[s][j].q0b = 0.0f;
            st[s][j].q1a = 0.0f; st[s][j].q1b = 0.0f;
        }

    // ---- A phase: projection + weights + exec-masked loads into st[buf] ----
    auto phaseA = [&](int k, int buf) {
        const float d  = dv[k];
        const float fx = (float)(xcol + k);
        #pragma unroll
        for (int j = 0; j < Vn; ++j) {
            const float* __restrict__ img = (j == 0) ? img0 : ((j == 1) ? img1 : img2);
            JState& s = st[buf][j];

            const float X = fmaf(d, fmaf(Q[j][0], fx, rx[j]), Q[j][3]);
            const float Y = fmaf(d, fmaf(Q[j][4], fx, ry[j]), Q[j][7]);
            s.Z           = fmaf(d, fmaf(Q[j][8], fx, rz[j]), Q[j][11]);

            const bool inb = (X >= 0.0f) & (X <= (float)(Wn - 1)) &
                             (Y >= 0.0f) & (Y <= (float)(Hn - 1));
            s.m = inb ? 1.0f : 0.0f;

            const float ix = fmaf(X, cW, -0.5f);
            const float iy = fmaf(Y, cH, -0.5f);
            const float x0f = floorf(ix);
            const float y0f = floorf(iy);
            const float wx1 = ix - x0f;
            const float wy1 = iy - y0f;
            const float wx0 = 1.0f - wx1;
            const float wy0 = 1.0f - wy1;
            const int x0 = (int)x0f;           // inb lanes: [-1, W-1]
            const int y0 = (int)y0f;           // inb lanes: [-1, H-1]

            const bool xlo = (x0 >= 0);
            const bool xhi = (x0 <= Wn - 2);
            const bool ylo = (y0 >= 0);
            const bool yhi = (y0 <= Hn - 2);
            const float wx0v = xlo ? wx0 : 0.0f;
            const float wx1v = xhi ? wx1 : 0.0f;
            s.wy0v = ylo ? wy0 : 0.0f;
            s.wy1v = yhi ? wy1 : 0.0f;
            const bool xin = xlo & xhi;
            s.wA = xin ? wx0v : wx1v;          // weight-swap == corner-swap
            s.wB = xin ? wx1v : wx0v;

            const int cy0 = max(y0, 0);
            const int cy1 = min(y0 + 1, Hn - 1);
            const int cx  = min(max(x0, 0), Wn - 2);
            const int a0  = cy0 * Wn + cx;
            const int a1  = cy1 * Wn + cx;

            if (inb) {                          // exec-masked: OOB lanes issue
                const fpair q0 = *reinterpret_cast<const fpair*>(img + a0);
                const fpair q1 = *reinterpret_cast<const fpair*>(img + a1);
                s.q0a = q0.a; s.q0b = q0.b;     // no memory requests (R3 lesson)
                s.q1a = q1.a; s.q1b = q1.b;     // stale values killed by m
            }
        }
    };

    // ---- B phase: pure-FMA consume, branch-free ----
    auto phaseB = [&](int buf) {
        #pragma unroll
        for (int j = 0; j < Vn; ++j) {
            JState& s = st[buf][j];
            const float row0 = fmaf(s.wA, s.q0a, s.wB * s.q0b);
            const float row1 = fmaf(s.wA, s.q1a, s.wB * s.q1b);
            const float warped = s.wy0v * row0 + s.wy1v * row1;
            num[j] += s.m * fabsf(warped - s.Z);
            den[j] += s.m;
        }
    };

    phaseA(0, 0);
    #pragma unroll
    for (int k = 0; k < PX; ++k) {
        if (k + 1 < PX) phaseA(k + 1, (k + 1) & 1);
        phaseB(k & 1);
    }

    // wave-64 shuffle reduction over 6 independent accumulators
    #pragma unroll
    for (int off = 32; off > 0; off >>= 1) {
        #pragma unroll
        for (int j = 0; j < Vn; ++j) {
            num[j] += __shfl_down(num[j], off, 64);
            den[j] += __shfl_down(den[j], off, 64);
        }
    }
    __shared__ float s_red[4][2 * Vn];
    const int lane = threadIdx.x & 63;
    const int wid  = threadIdx.x >> 6;
    if (lane == 0) {
        #pragma unroll
        for (int j = 0; j < Vn; ++j) {
            s_red[wid][2 * j + 0] = num[j];
            s_red[wid][2 * j + 1] = den[j];
        }
    }
    __syncthreads();
    // per-block partial store: no init needed, no atomics, no fence
    if (threadIdx.x < 2 * Vn) {
        const int slot = threadIdx.x;
        const float v = s_red[0][slot] + s_red[1][slot] + s_red[2][slot] + s_red[3][slot];
        part[(size_t)id * 8 + slot] = v;
    }
}

// ---------- Finalize: sum 1920 partials -> 9 pair accums -> total ----------
__global__ __launch_bounds__(TPB) void finalize_kernel(const float* __restrict__ part,
                                                       float* __restrict__ out) {
    float acc[2 * Vn * Vn];   // [pair*2 + comp], pair = i*3+j
    #pragma unroll
    for (int s = 0; s < 2 * Vn * Vn; ++s) acc[s] = 0.0f;

    for (int m = threadIdx.x; m < GRIDN; m += TPB) {
        const int i = (m >> 3) % Vn;
        const float* pp = part + (size_t)m * 8;
        #pragma unroll
        for (int j = 0; j < Vn; ++j) {
            acc[(i * Vn + j) * 2 + 0] += pp[2 * j + 0];
            acc[(i * Vn + j) * 2 + 1] += pp[2 * j + 1];
        }
    }
    #pragma unroll
    for (int off = 32; off > 0; off >>= 1) {
        #pragma unroll
        for (int s = 0; s < 2 * Vn * Vn; ++s)
            acc[s] += __shfl_down(acc[s], off, 64);
    }
    __shared__ float s_fin[4][2 * Vn * Vn];
    const int lane = threadIdx.x & 63;
    const int wid  = threadIdx.x >> 6;
    if (lane == 0) {
        #pragma unroll
        for (int s = 0; s < 2 * Vn * Vn; ++s) s_fin[wid][s] = acc[s];
    }
    __syncthreads();
    if (threadIdx.x == 0) {
        float t = 0.0f;
        #pragma unroll
        for (int pr = 0; pr < Vn * Vn; ++pr) {
            const float nn = s_fin[0][pr*2+0] + s_fin[1][pr*2+0] + s_fin[2][pr*2+0] + s_fin[3][pr*2+0];
            const float dd = s_fin[0][pr*2+1] + s_fin[1][pr*2+1] + s_fin[2][pr*2+1] + s_fin[3][pr*2+1];
            t += nn / fmaxf(dd, 1.0f);
        }
        out[0] = t;
    }
}

extern "C" void kernel_launch(void* const* d_in, const int* in_sizes, int n_in,
                              void* d_out, int out_size, void* d_ws, size_t ws_size,
                              hipStream_t stream) {
    const float* pred = (const float*)d_in[0];   // (B,V,H,W)
    const float* K    = (const float*)d_in[1];   // (B,4,4)
    const float* RT   = (const float*)d_in[2];   // (B,V,4,4)
    float* out = (float*)d_out;

    float* part = (float*)d_ws;                  // GRIDN*8 floats, fully overwritten

    loss_main_kernel<<<GRIDN, TPB, 0, stream>>>(pred, K, RT, part);
    finalize_kernel<<<1, TPB, 0, stream>>>(part, out);
}

// Round 6
// 611.966 us; speedup vs baseline: 1.2476x; 1.2476x over previous
//
#include <hip/hip_runtime.h>

#define Bn 8
#define Vn 3
#define Hn 512
#define Wn 640
#define Nn (Hn * Wn)
#define PX 16                     // pixels per thread (16 divides 640: no row wrap)
#define TPB 256
#define XBLKS (Nn / (TPB * PX))   // 80
#define GRIDN (XBLKS * Vn * Bn)   // 1920 blocks

struct __attribute__((aligned(4))) fpair { float a, b; };

__device__ __forceinline__ float rfl(float x) {
    return __int_as_float(__builtin_amdgcn_readfirstlane(__float_as_int(x)));
}

// Inline P = K * RT_j * inv(RT_i) * inv(K), rows 0..2, analytic affine inverses.
// Bottom row of P is exactly [0,0,0,1]. Validated: absmax 0.0 vs reference.
__device__ __forceinline__ void computeQ(const float* __restrict__ K,
                                         const float* __restrict__ RT,
                                         int b, int i, float Q[Vn][12]) {
    const float* Kb = K + (size_t)b * 16;
    const float f  = Kb[0], cx = Kb[2], cy = Kb[6];
    const float rf = 1.0f / f;
    const float* Ti = RT + (size_t)(b * Vn + i) * 16;
    const float A00=Ti[0], A01=Ti[1], A02=Ti[2],  A03=Ti[3];
    const float A10=Ti[4], A11=Ti[5], A12=Ti[6],  A13=Ti[7];
    const float A20=Ti[8], A21=Ti[9], A22=Ti[10], A23=Ti[11];
    const float I00=A00, I01=A10, I02=A20, I03=-(A00*A03 + A10*A13 + A20*A23);
    const float I10=A01, I11=A11, I12=A21, I13=-(A01*A03 + A11*A13 + A21*A23);
    const float I20=A02, I21=A12, I22=A22, I23=-(A02*A03 + A12*A13 + A22*A23);
    #pragma unroll
    for (int j = 0; j < Vn; ++j) {
        const float* Tj = RT + (size_t)(b * Vn + j) * 16;
        const float B00=Tj[0], B01=Tj[1], B02=Tj[2],  B03=Tj[3];
        const float B10=Tj[4], B11=Tj[5], B12=Tj[6],  B13=Tj[7];
        const float B20=Tj[8], B21=Tj[9], B22=Tj[10], B23=Tj[11];
        const float M00=B00*I00+B01*I10+B02*I20, M01=B00*I01+B01*I11+B02*I21,
                    M02=B00*I02+B01*I12+B02*I22, M03=B00*I03+B01*I13+B02*I23+B03;
        const float M10=B10*I00+B11*I10+B12*I20, M11=B10*I01+B11*I11+B12*I21,
                    M12=B10*I02+B11*I12+B12*I22, M13=B10*I03+B11*I13+B12*I23+B13;
        const float M20=B20*I00+B21*I10+B22*I20, M21=B20*I01+B21*I11+B22*I21,
                    M22=B20*I02+B21*I12+B22*I22, M23=B20*I03+B21*I13+B22*I23+B23;
        const float G00=f*M00+cx*M20, G01=f*M01+cx*M21, G02=f*M02+cx*M22, G03=f*M03+cx*M23;
        const float G10=f*M10+cy*M20, G11=f*M11+cy*M21, G12=f*M12+cy*M22, G13=f*M13+cy*M23;
        const float G20=M20,          G21=M21,          G22=M22,          G23=M23;
        Q[j][0]  = rfl(G00*rf);  Q[j][1]  = rfl(G01*rf);
        Q[j][2]  = rfl(G02 - (cx*rf)*G00 - (cy*rf)*G01);  Q[j][3]  = rfl(G03);
        Q[j][4]  = rfl(G10*rf);  Q[j][5]  = rfl(G11*rf);
        Q[j][6]  = rfl(G12 - (cx*rf)*G10 - (cy*rf)*G11);  Q[j][7]  = rfl(G13);
        Q[j][8]  = rfl(G20*rf);  Q[j][9]  = rfl(G21*rf);
        Q[j][10] = rfl(G22 - (cx*rf)*G20 - (cy*rf)*G21);  Q[j][11] = rfl(G23);
    }
}

// Pipeline state for one pixel x one source view j.
// wA/wB encode the border corner-swap as a WEIGHT swap (proof in R24 notes):
//   interior: (wA,wB) = (wx0v,wx1v) -> identical to the old fast path
//   x-border: (wA,wB) swapped      -> identical to the old masked path.
// m = inb ? 1.0 : 0.0 kills OOB contributions exactly (images > 0, weights
// in [0,1], stale q regs finite -> no -0/NaN hazards; 1.0f*x is bitwise x).
struct JState {
    float q0a, q0b, q1a, q1b;
    float wA, wB, wy0v, wy1v;
    float Z, m;
};

// ---------- Main: R26 spill-proof 1-deep software pipeline ----------
// R25 post-mortem: runtime-indexed st[buf] (rule #20) sent ALL state to
// scratch (VGPR=40, WRITE_SIZE 1.1 GB, 17x regression) -> theory untested.
// This version: two NAMED buffers st0/st1, alternation fully static (k-loop
// unrolled by 2, each half hard-codes its buffer), all j indices literal.
// __launch_bounds__(256,4): VGPR cap 128 -> no spill for ~60 floats of state.
// A-phase: projection+weights+exec-masked loads into named regs. B-phase:
// pure-FMA consume, zero branches. 6 loads in flight during each consume.
__global__ __launch_bounds__(TPB, 4) void loss_main_kernel(const float* __restrict__ pred,
                                                           const float* __restrict__ K,
                                                           const float* __restrict__ RT,
                                                           float* __restrict__ part) {
    // b = blockIdx.x % 8: XCD-batch L2 locality (one batch's 3 planes = 3.93 MB).
    const int id   = blockIdx.x;
    const int b    = id & 7;
    const int r    = id >> 3;
    const int i    = r % Vn;
    const int xblk = r / Vn;           // 0..79

    float Q[Vn][12];
    computeQ(K, RT, b, i, Q);

    // R20 balance bijection over the 512x40 segment grid (kept):
    const int tid  = threadIdx.x;
    const int h    = (xblk >= 40) ? 1 : 0;
    const int c0   = xblk - 40 * h;
    const int yrow = 2 * tid + h;
    int c = c0 + tid;
    c -= (c / 40) * 40;
    const int xcol = c << 4;
    const int base = yrow * Wn + xcol;
    const float fy = (float)yrow;

    const float* dptr = pred + (size_t)(b * Vn + i) * Nn + base;
    float dv[PX];
    {
        const float4 a0 = *reinterpret_cast<const float4*>(dptr);
        const float4 a1 = *reinterpret_cast<const float4*>(dptr + 4);
        const float4 a2 = *reinterpret_cast<const float4*>(dptr + 8);
        const float4 a3 = *reinterpret_cast<const float4*>(dptr + 12);
        dv[0]=a0.x; dv[1]=a0.y; dv[2]=a0.z; dv[3]=a0.w;
        dv[4]=a1.x; dv[5]=a1.y; dv[6]=a1.z; dv[7]=a1.w;
        dv[8]=a2.x; dv[9]=a2.y; dv[10]=a2.z; dv[11]=a2.w;
        dv[12]=a3.x; dv[13]=a3.y; dv[14]=a3.z; dv[15]=a3.w;
    }

    const float cW = (float)Wn / (float)(Wn - 1);   // ix = X*cW - 0.5
    const float cH = (float)Hn / (float)(Hn - 1);

    float num[Vn] = {0.0f, 0.0f, 0.0f};
    float den[Vn] = {0.0f, 0.0f, 0.0f};

    float rx[Vn], ry[Vn], rz[Vn];
    #pragma unroll
    for (int j = 0; j < Vn; ++j) {
        rx[j] = fmaf(Q[j][1], fy, Q[j][2]);
        ry[j] = fmaf(Q[j][5], fy, Q[j][6]);
        rz[j] = fmaf(Q[j][9], fy, Q[j][10]);
    }

    const float* __restrict__ img0 = pred + (size_t)(b * Vn + 0) * Nn;
    const float* __restrict__ img1 = pred + (size_t)(b * Vn + 1) * Nn;
    const float* __restrict__ img2 = pred + (size_t)(b * Vn + 2) * Nn;

    JState st0[Vn], st1[Vn];
    #pragma unroll
    for (int j = 0; j < Vn; ++j) {
        st0[j].q0a = 0.0f; st0[j].q0b = 0.0f; st0[j].q1a = 0.0f; st0[j].q1b = 0.0f;
        st1[j].q0a = 0.0f; st1[j].q0b = 0.0f; st1[j].q1a = 0.0f; st1[j].q1b = 0.0f;
    }

    // ---- A phase: projection + weights + exec-masked loads into s[] ----
    auto phaseA = [&](int k, JState (&s)[Vn]) {
        const float d  = dv[k];                  // k is compile-time (unrolled)
        const float fx = (float)(xcol + k);
        #pragma unroll
        for (int j = 0; j < Vn; ++j) {
            const float* __restrict__ img = (j == 0) ? img0 : ((j == 1) ? img1 : img2);

            const float X = fmaf(d, fmaf(Q[j][0], fx, rx[j]), Q[j][3]);
            const float Y = fmaf(d, fmaf(Q[j][4], fx, ry[j]), Q[j][7]);
            s[j].Z        = fmaf(d, fmaf(Q[j][8], fx, rz[j]), Q[j][11]);

            const bool inb = (X >= 0.0f) & (X <= (float)(Wn - 1)) &
                             (Y >= 0.0f) & (Y <= (float)(Hn - 1));
            s[j].m = inb ? 1.0f : 0.0f;

            const float ix = fmaf(X, cW, -0.5f);
            const float iy = fmaf(Y, cH, -0.5f);
            const float x0f = floorf(ix);
            const float y0f = floorf(iy);
            const float wx1 = ix - x0f;
            const float wy1 = iy - y0f;
            const float wx0 = 1.0f - wx1;
            const float wy0 = 1.0f - wy1;
            const int x0 = (int)x0f;           // inb lanes: [-1, W-1]
            const int y0 = (int)y0f;           // inb lanes: [-1, H-1]

            const bool xlo = (x0 >= 0);
            const bool xhi = (x0 <= Wn - 2);
            const bool ylo = (y0 >= 0);
            const bool yhi = (y0 <= Hn - 2);
            const float wx0v = xlo ? wx0 : 0.0f;
            const float wx1v = xhi ? wx1 : 0.0f;
            s[j].wy0v = ylo ? wy0 : 0.0f;
            s[j].wy1v = yhi ? wy1 : 0.0f;
            const bool xin = xlo & xhi;
            s[j].wA = xin ? wx0v : wx1v;       // weight-swap == corner-swap
            s[j].wB = xin ? wx1v : wx0v;

            const int cy0 = max(y0, 0);
            const int cy1 = min(y0 + 1, Hn - 1);
            const int cx  = min(max(x0, 0), Wn - 2);
            const int a0  = cy0 * Wn + cx;
            const int a1  = cy1 * Wn + cx;

            if (inb) {                          // exec-masked: OOB lanes issue
                const fpair q0 = *reinterpret_cast<const fpair*>(img + a0);
                const fpair q1 = *reinterpret_cast<const fpair*>(img + a1);
                s[j].q0a = q0.a; s[j].q0b = q0.b;   // no requests (R3 lesson)
                s[j].q1a = q1.a; s[j].q1b = q1.b;   // stale regs killed by m
            }
        }
    };

    // ---- B phase: pure-FMA consume, branch-free ----
    auto phaseB = [&](JState (&s)[Vn]) {
        #pragma unroll
        for (int j = 0; j < Vn; ++j) {
            const float row0 = fmaf(s[j].wA, s[j].q0a, s[j].wB * s[j].q0b);
            const float row1 = fmaf(s[j].wA, s[j].q1a, s[j].wB * s[j].q1b);
            const float warped = s[j].wy0v * row0 + s[j].wy1v * row1;
            num[j] += s[j].m * fabsf(warped - s[j].Z);
            den[j] += s[j].m;
        }
    };

    // Static 1-deep pipeline: buffers hard-coded per position, k unrolled.
    phaseA(0, st0);
    #pragma unroll
    for (int kk = 0; kk < PX; kk += 2) {
        phaseA(kk + 1, st1);                 // kk+1 <= 15 always (PX even)
        phaseB(st0);                         // consume pixel kk
        if (kk + 2 < PX) phaseA(kk + 2, st0);
        phaseB(st1);                         // consume pixel kk+1
    }

    // wave-64 shuffle reduction over 6 independent accumulators
    #pragma unroll
    for (int off = 32; off > 0; off >>= 1) {
        #pragma unroll
        for (int j = 0; j < Vn; ++j) {
            num[j] += __shfl_down(num[j], off, 64);
            den[j] += __shfl_down(den[j], off, 64);
        }
    }
    __shared__ float s_red[4][2 * Vn];
    const int lane = threadIdx.x & 63;
    const int wid  = threadIdx.x >> 6;
    if (lane == 0) {
        #pragma unroll
        for (int j = 0; j < Vn; ++j) {
            s_red[wid][2 * j + 0] = num[j];
            s_red[wid][2 * j + 1] = den[j];
        }
    }
    __syncthreads();
    // per-block partial store: no init needed, no atomics, no fence
    if (threadIdx.x < 2 * Vn) {
        const int slot = threadIdx.x;
        const float v = s_red[0][slot] + s_red[1][slot] + s_red[2][slot] + s_red[3][slot];
        part[(size_t)id * 8 + slot] = v;
    }
}

// ---------- Finalize: sum 1920 partials -> 9 pair accums -> total ----------
__global__ __launch_bounds__(TPB) void finalize_kernel(const float* __restrict__ part,
                                                       float* __restrict__ out) {
    float acc[2 * Vn * Vn];   // [pair*2 + comp], pair = i*3+j
    #pragma unroll
    for (int s = 0; s < 2 * Vn * Vn; ++s) acc[s] = 0.0f;

    for (int m = threadIdx.x; m < GRIDN; m += TPB) {
        const int i = (m >> 3) % Vn;
        const float* pp = part + (size_t)m * 8;
        #pragma unroll
        for (int j = 0; j < Vn; ++j) {
            acc[(i * Vn + j) * 2 + 0] += pp[2 * j + 0];
            acc[(i * Vn + j) * 2 + 1] += pp[2 * j + 1];
        }
    }
    #pragma unroll
    for (int off = 32; off > 0; off >>= 1) {
        #pragma unroll
        for (int s = 0; s < 2 * Vn * Vn; ++s)
            acc[s] += __shfl_down(acc[s], off, 64);
    }
    __shared__ float s_fin[4][2 * Vn * Vn];
    const int lane = threadIdx.x & 63;
    const int wid  = threadIdx.x >> 6;
    if (lane == 0) {
        #pragma unroll
        for (int s = 0; s < 2 * Vn * Vn; ++s) s_fin[wid][s] = acc[s];
    }
    __syncthreads();
    if (threadIdx.x == 0) {
        float t = 0.0f;
        #pragma unroll
        for (int pr = 0; pr < Vn * Vn; ++pr) {
            const float nn = s_fin[0][pr*2+0] + s_fin[1][pr*2+0] + s_fin[2][pr*2+0] + s_fin[3][pr*2+0];
            const float dd = s_fin[0][pr*2+1] + s_fin[1][pr*2+1] + s_fin[2][pr*2+1] + s_fin[3][pr*2+1];
            t += nn / fmaxf(dd, 1.0f);
        }
        out[0] = t;
    }
}

extern "C" void kernel_launch(void* const* d_in, const int* in_sizes, int n_in,
                              void* d_out, int out_size, void* d_ws, size_t ws_size,
                              hipStream_t stream) {
    const float* pred = (const float*)d_in[0];   // (B,V,H,W)
    const float* K    = (const float*)d_in[1];   // (B,4,4)
    const float* RT   = (const float*)d_in[2];   // (B,V,4,4)
    float* out = (float*)d_out;

    float* part = (float*)d_ws;                  // GRIDN*8 floats, fully overwritten

    loss_main_kernel<<<GRIDN, TPB, 0, stream>>>(pred, K, RT, part);
    finalize_kernel<<<1, TPB, 0, stream>>>(part, out);
}

// Round 7
// 610.327 us; speedup vs baseline: 1.2509x; 1.0027x over previous
//
#include <hip/hip_runtime.h>

#define Bn 8
#define Vn 3
#define Hn 512
#define Wn 640
#define Nn (Hn * Wn)
#define PX 16                     // pixels per thread (16 divides 640: no row wrap)
#define TPB 256
#define XBLKS (Nn / (TPB * PX))   // 80
#define GRIDN (XBLKS * Vn * Bn)   // 1920 blocks

struct __attribute__((aligned(4))) fpair { float a, b; };

__device__ __forceinline__ float rfl(float x) {
    return __int_as_float(__builtin_amdgcn_readfirstlane(__float_as_int(x)));
}

// Inline P = K * RT_j * inv(RT_i) * inv(K), rows 0..2, analytic affine inverses.
// Bottom row of P is exactly [0,0,0,1]. Validated: absmax 0.0 vs reference.
__device__ __forceinline__ void computeQ(const float* __restrict__ K,
                                         const float* __restrict__ RT,
                                         int b, int i, float Q[Vn][12]) {
    const float* Kb = K + (size_t)b * 16;
    const float f  = Kb[0], cx = Kb[2], cy = Kb[6];
    const float rf = 1.0f / f;
    const float* Ti = RT + (size_t)(b * Vn + i) * 16;
    const float A00=Ti[0], A01=Ti[1], A02=Ti[2],  A03=Ti[3];
    const float A10=Ti[4], A11=Ti[5], A12=Ti[6],  A13=Ti[7];
    const float A20=Ti[8], A21=Ti[9], A22=Ti[10], A23=Ti[11];
    const float I00=A00, I01=A10, I02=A20, I03=-(A00*A03 + A10*A13 + A20*A23);
    const float I10=A01, I11=A11, I12=A21, I13=-(A01*A03 + A11*A13 + A21*A23);
    const float I20=A02, I21=A12, I22=A22, I23=-(A02*A03 + A12*A13 + A22*A23);
    #pragma unroll
    for (int j = 0; j < Vn; ++j) {
        const float* Tj = RT + (size_t)(b * Vn + j) * 16;
        const float B00=Tj[0], B01=Tj[1], B02=Tj[2],  B03=Tj[3];
        const float B10=Tj[4], B11=Tj[5], B12=Tj[6],  B13=Tj[7];
        const float B20=Tj[8], B21=Tj[9], B22=Tj[10], B23=Tj[11];
        const float M00=B00*I00+B01*I10+B02*I20, M01=B00*I01+B01*I11+B02*I21,
                    M02=B00*I02+B01*I12+B02*I22, M03=B00*I03+B01*I13+B02*I23+B03;
        const float M10=B10*I00+B11*I10+B12*I20, M11=B10*I01+B11*I11+B12*I21,
                    M12=B10*I02+B11*I12+B12*I22, M13=B10*I03+B11*I13+B12*I23+B13;
        const float M20=B20*I00+B21*I10+B22*I20, M21=B20*I01+B21*I11+B22*I21,
                    M22=B20*I02+B21*I12+B22*I22, M23=B20*I03+B21*I13+B22*I23+B23;
        const float G00=f*M00+cx*M20, G01=f*M01+cx*M21, G02=f*M02+cx*M22, G03=f*M03+cx*M23;
        const float G10=f*M10+cy*M20, G11=f*M11+cy*M21, G12=f*M12+cy*M22, G13=f*M13+cy*M23;
        const float G20=M20,          G21=M21,          G22=M22,          G23=M23;
        Q[j][0]  = rfl(G00*rf);  Q[j][1]  = rfl(G01*rf);
        Q[j][2]  = rfl(G02 - (cx*rf)*G00 - (cy*rf)*G01);  Q[j][3]  = rfl(G03);
        Q[j][4]  = rfl(G10*rf);  Q[j][5]  = rfl(G11*rf);
        Q[j][6]  = rfl(G12 - (cx*rf)*G10 - (cy*rf)*G11);  Q[j][7]  = rfl(G13);
        Q[j][8]  = rfl(G20*rf);  Q[j][9]  = rfl(G21*rf);
        Q[j][10] = rfl(G22 - (cx*rf)*G20 - (cy*rf)*G21);  Q[j][11] = rfl(G23);
    }
}

// ---------- R27: pipeline state as NAMED SCALARS (no arrays/structs/lambdas) ----------
// R25/R26 post-mortem: lambdas taking state arrays by reference kept the state
// addressable -> alloca survived -> scratch (WRITE_SIZE 862 MB, VGPR=64).
// All state is now 60 individually-named floats via token-pasting macros; the
// 16-pixel pipeline is 33 explicit macro invocations with LITERAL k. Nothing
// is runtime-indexed except the (SROA-proven) dv/Q/r*/num/den arrays of R1.
//
// Body semantics (HW-validated bitwise-exact in R5/R6, absmax 0.0):
//  - weight-swap uniform consume: (wA,wB) swapped at x-borders == corner swap
//  - m in {0,1} multiply kills OOB contributions exactly (finite garbage * 0)
//  - loads exec-masked by if(inb): OOB lanes issue NO memory requests (R3)
//  - per-j accumulation over k stays ascending -> bitwise-identical total

#define ST_DECL(S) \
    float S##q0a = 0.0f, S##q0b = 0.0f, S##q1a = 0.0f, S##q1b = 0.0f; \
    float S##wA, S##wB, S##wy0, S##wy1, S##Z, S##m;

#define PA(S, J, IMG, Kk) { \
    const float d_  = dv[Kk]; \
    const float fx_ = (float)(xcol + Kk); \
    const float X_ = fmaf(d_, fmaf(Q[J][0], fx_, rx[J]), Q[J][3]); \
    const float Y_ = fmaf(d_, fmaf(Q[J][4], fx_, ry[J]), Q[J][7]); \
    S##Z = fmaf(d_, fmaf(Q[J][8], fx_, rz[J]), Q[J][11]); \
    const bool inb_ = (X_ >= 0.0f) & (X_ <= (float)(Wn - 1)) & \
                      (Y_ >= 0.0f) & (Y_ <= (float)(Hn - 1)); \
    S##m = inb_ ? 1.0f : 0.0f; \
    const float ix_  = fmaf(X_, cW, -0.5f); \
    const float iy_  = fmaf(Y_, cH, -0.5f); \
    const float x0f_ = floorf(ix_); \
    const float y0f_ = floorf(iy_); \
    const float wx1_ = ix_ - x0f_; \
    const float wy1_ = iy_ - y0f_; \
    const float wx0_ = 1.0f - wx1_; \
    const float wy0_ = 1.0f - wy1_; \
    const int x0_ = (int)x0f_; \
    const int y0_ = (int)y0f_; \
    const bool xlo_ = (x0_ >= 0); \
    const bool xhi_ = (x0_ <= Wn - 2); \
    const float wx0v_ = xlo_ ? wx0_ : 0.0f; \
    const float wx1v_ = xhi_ ? wx1_ : 0.0f; \
    S##wy0 = (y0_ >= 0)      ? wy0_ : 0.0f; \
    S##wy1 = (y0_ <= Hn - 2) ? wy1_ : 0.0f; \
    const bool xin_ = xlo_ & xhi_; \
    S##wA = xin_ ? wx0v_ : wx1v_; \
    S##wB = xin_ ? wx1v_ : wx0v_; \
    const int cy0_ = max(y0_, 0); \
    const int cy1_ = min(y0_ + 1, Hn - 1); \
    const int cx_  = min(max(x0_, 0), Wn - 2); \
    if (inb_) { \
        const fpair q0_ = *reinterpret_cast<const fpair*>(IMG + (cy0_ * Wn + cx_)); \
        const fpair q1_ = *reinterpret_cast<const fpair*>(IMG + (cy1_ * Wn + cx_)); \
        S##q0a = q0_.a; S##q0b = q0_.b; \
        S##q1a = q1_.a; S##q1b = q1_.b; \
    } }

#define PB(S, J) { \
    const float row0_ = fmaf(S##wA, S##q0a, S##wB * S##q0b); \
    const float row1_ = fmaf(S##wA, S##q1a, S##wB * S##q1b); \
    const float warped_ = S##wy0 * row0_ + S##wy1 * row1_; \
    num[J] += S##m * fabsf(warped_ - S##Z); \
    den[J] += S##m; }

#define STEPA(BUF, Kk) PA(BUF##0_, 0, img0, Kk) PA(BUF##1_, 1, img1, Kk) PA(BUF##2_, 2, img2, Kk)
#define STEPB(BUF)     PB(BUF##0_, 0)           PB(BUF##1_, 1)           PB(BUF##2_, 2)

__global__ __launch_bounds__(TPB, 4) void loss_main_kernel(const float* __restrict__ pred,
                                                           const float* __restrict__ K,
                                                           const float* __restrict__ RT,
                                                           float* __restrict__ part) {
    // b = blockIdx.x % 8: XCD-batch L2 locality (one batch's 3 planes = 3.93 MB).
    const int id   = blockIdx.x;
    const int b    = id & 7;
    const int r    = id >> 3;
    const int i    = r % Vn;
    const int xblk = r / Vn;           // 0..79

    float Q[Vn][12];
    computeQ(K, RT, b, i, Q);

    // R20 balance bijection over the 512x40 segment grid (kept):
    const int tid  = threadIdx.x;
    const int h    = (xblk >= 40) ? 1 : 0;
    const int c0   = xblk - 40 * h;
    const int yrow = 2 * tid + h;
    int c = c0 + tid;
    c -= (c / 40) * 40;
    const int xcol = c << 4;
    const int base = yrow * Wn + xcol;
    const float fy = (float)yrow;

    const float* dptr = pred + (size_t)(b * Vn + i) * Nn + base;
    float dv[PX];
    {
        const float4 a0 = *reinterpret_cast<const float4*>(dptr);
        const float4 a1 = *reinterpret_cast<const float4*>(dptr + 4);
        const float4 a2 = *reinterpret_cast<const float4*>(dptr + 8);
        const float4 a3 = *reinterpret_cast<const float4*>(dptr + 12);
        dv[0]=a0.x; dv[1]=a0.y; dv[2]=a0.z; dv[3]=a0.w;
        dv[4]=a1.x; dv[5]=a1.y; dv[6]=a1.z; dv[7]=a1.w;
        dv[8]=a2.x; dv[9]=a2.y; dv[10]=a2.z; dv[11]=a2.w;
        dv[12]=a3.x; dv[13]=a3.y; dv[14]=a3.z; dv[15]=a3.w;
    }

    const float cW = (float)Wn / (float)(Wn - 1);   // ix = X*cW - 0.5
    const float cH = (float)Hn / (float)(Hn - 1);

    float num[Vn] = {0.0f, 0.0f, 0.0f};
    float den[Vn] = {0.0f, 0.0f, 0.0f};

    float rx[Vn], ry[Vn], rz[Vn];
    #pragma unroll
    for (int j = 0; j < Vn; ++j) {
        rx[j] = fmaf(Q[j][1], fy, Q[j][2]);
        ry[j] = fmaf(Q[j][5], fy, Q[j][6]);
        rz[j] = fmaf(Q[j][9], fy, Q[j][10]);
    }

    const float* __restrict__ img0 = pred + (size_t)(b * Vn + 0) * Nn;
    const float* __restrict__ img1 = pred + (size_t)(b * Vn + 1) * Nn;
    const float* __restrict__ img2 = pred + (size_t)(b * Vn + 2) * Nn;

    // 60 named scalar state floats (2 buffers x 3 views x 10).
    ST_DECL(a0_) ST_DECL(a1_) ST_DECL(a2_)
    ST_DECL(b0_) ST_DECL(b1_) ST_DECL(b2_)

    // ---- static 1-deep pipeline, literal k everywhere ----
    STEPA(a, 0)
    STEPA(b, 1)  STEPB(a)
    STEPA(a, 2)  STEPB(b)
    STEPA(b, 3)  STEPB(a)
    STEPA(a, 4)  STEPB(b)
    STEPA(b, 5)  STEPB(a)
    STEPA(a, 6)  STEPB(b)
    STEPA(b, 7)  STEPB(a)
    STEPA(a, 8)  STEPB(b)
    STEPA(b, 9)  STEPB(a)
    STEPA(a, 10) STEPB(b)
    STEPA(b, 11) STEPB(a)
    STEPA(a, 12) STEPB(b)
    STEPA(b, 13) STEPB(a)
    STEPA(a, 14) STEPB(b)
    STEPA(b, 15) STEPB(a)
    STEPB(b)

    // wave-64 shuffle reduction over 6 independent accumulators
    #pragma unroll
    for (int off = 32; off > 0; off >>= 1) {
        #pragma unroll
        for (int j = 0; j < Vn; ++j) {
            num[j] += __shfl_down(num[j], off, 64);
            den[j] += __shfl_down(den[j], off, 64);
        }
    }
    __shared__ float s_red[4][2 * Vn];
    const int lane = threadIdx.x & 63;
    const int wid  = threadIdx.x >> 6;
    if (lane == 0) {
        #pragma unroll
        for (int j = 0; j < Vn; ++j) {
            s_red[wid][2 * j + 0] = num[j];
            s_red[wid][2 * j + 1] = den[j];
        }
    }
    __syncthreads();
    // per-block partial store: no init needed, no atomics, no fence
    if (threadIdx.x < 2 * Vn) {
        const int slot = threadIdx.x;
        const float v = s_red[0][slot] + s_red[1][slot] + s_red[2][slot] + s_red[3][slot];
        part[(size_t)id * 8 + slot] = v;
    }
}

// ---------- Finalize: sum 1920 partials -> 9 pair accums -> total ----------
__global__ __launch_bounds__(TPB) void finalize_kernel(const float* __restrict__ part,
                                                       float* __restrict__ out) {
    float acc[2 * Vn * Vn];   // [pair*2 + comp], pair = i*3+j
    #pragma unroll
    for (int s = 0; s < 2 * Vn * Vn; ++s) acc[s] = 0.0f;

    for (int m = threadIdx.x; m < GRIDN; m += TPB) {
        const int i = (m >> 3) % Vn;
        const float* pp = part + (size_t)m * 8;
        #pragma unroll
        for (int j = 0; j < Vn; ++j) {
            acc[(i * Vn + j) * 2 + 0] += pp[2 * j + 0];
            acc[(i * Vn + j) * 2 + 1] += pp[2 * j + 1];
        }
    }
    #pragma unroll
    for (int off = 32; off > 0; off >>= 1) {
        #pragma unroll
        for (int s = 0; s < 2 * Vn * Vn; ++s)
            acc[s] += __shfl_down(acc[s], off, 64);
    }
    __shared__ float s_fin[4][2 * Vn * Vn];
    const int lane = threadIdx.x & 63;
    const int wid  = threadIdx.x >> 6;
    if (lane == 0) {
        #pragma unroll
        for (int s = 0; s < 2 * Vn * Vn; ++s) s_fin[wid][s] = acc[s];
    }
    __syncthreads();
    if (threadIdx.x == 0) {
        float t = 0.0f;
        #pragma unroll
        for (int pr = 0; pr < Vn * Vn; ++pr) {
            const float nn = s_fin[0][pr*2+0] + s_fin[1][pr*2+0] + s_fin[2][pr*2+0] + s_fin[3][pr*2+0];
            const float dd = s_fin[0][pr*2+1] + s_fin[1][pr*2+1] + s_fin[2][pr*2+1] + s_fin[3][pr*2+1];
            t += nn / fmaxf(dd, 1.0f);
        }
        out[0] = t;
    }
}

extern "C" void kernel_launch(void* const* d_in, const int* in_sizes, int n_in,
                              void* d_out, int out_size, void* d_ws, size_t ws_size,
                              hipStream_t stream) {
    const float* pred = (const float*)d_in[0];   // (B,V,H,W)
    const float* K    = (const float*)d_in[1];   // (B,4,4)
    const float* RT   = (const float*)d_in[2];   // (B,V,4,4)
    float* out = (float*)d_out;

    float* part = (float*)d_ws;                  // GRIDN*8 floats, fully overwritten

    loss_main_kernel<<<GRIDN, TPB, 0, stream>>>(pred, K, RT, part);
    finalize_kernel<<<1, TPB, 0, stream>>>(part, out);
}

// Round 8
// 125.445 us; speedup vs baseline: 6.0861x; 4.8653x over previous
//
#include <hip/hip_runtime.h>
#include <hip/hip_fp16.h>

#define Bn 8
#define Vn 3
#define Hn 512
#define Wn 640
#define Nn (Hn * Wn)
#define PX 16                     // pixels per thread (16 divides 640: no row wrap)
#define TPB 256
#define XBLKS (Nn / (TPB * PX))   // 80
#define GRIDN (XBLKS * Vn * Bn)   // 1920 blocks

#define JOFF_PART (64 * 1024 * 1024 / 4)      // float offset of partials in ws (64 MB)
#define PRE_TPB 256
#define PRE_UNITS (Bn * Vn * Nn / 4)          // 1,966,080 (4 px per thread)
#define PRE_GRID (PRE_UNITS / PRE_TPB)        // 7680

struct __attribute__((aligned(4))) fpair { float a, b; };
// One pixel of the fp16 row-pair image: r0 = (I[y][x], I[y+1][x]) packed lo/hi.
// Loading h2q at [y0*W+x0] yields the full 2x2 bilinear quad in 8 bytes.
struct __attribute__((aligned(4))) h2q { __half2 r0, r1; };

__device__ __forceinline__ float rfl(float x) {
    return __int_as_float(__builtin_amdgcn_readfirstlane(__float_as_int(x)));
}

// ---------- Prepass: J16[plane][y][x] = half2(I[y][x], I[y+1][x]) ----------
// R28 model: kernel is TCP *dword-lane* throughput bound (~4 dw/cy/CU). fp32
// floor is 4 dw-lanes/sample (2 rows x 8B); fp16 row-pair packs the quad into
// ONE 8B load = 2 dw-lanes/sample. Weights/Z/mask stay fp32 (depth read from
// fp32 pred) -> only corner VALUES are RN-rounded; est. total error ~1e-5.
__global__ __launch_bounds__(PRE_TPB) void prepass_kernel(const float* __restrict__ pred,
                                                          __half2* __restrict__ J16) {
    const int t     = blockIdx.x * PRE_TPB + threadIdx.x;
    const int plane = t / (Nn / 4);
    const int rem   = t - plane * (Nn / 4);
    const int y     = rem / (Wn / 4);
    const int x4    = (rem - y * (Wn / 4)) * 4;
    const float* src = pred + (size_t)plane * Nn;
    const int yn = (y < Hn - 1) ? y + 1 : y;      // last row duplicates (never read)
    const float4 r0 = *reinterpret_cast<const float4*>(src + y  * Wn + x4);
    const float4 r1 = *reinterpret_cast<const float4*>(src + yn * Wn + x4);
    struct __attribute__((aligned(16))) h2x4 { __half2 a, b, c, d; } o;
    o.a = __floats2half2_rn(r0.x, r1.x);
    o.b = __floats2half2_rn(r0.y, r1.y);
    o.c = __floats2half2_rn(r0.z, r1.z);
    o.d = __floats2half2_rn(r0.w, r1.w);
    *reinterpret_cast<h2x4*>(J16 + (size_t)plane * Nn + y * Wn + x4) = o;
}

// Inline P = K * RT_j * inv(RT_i) * inv(K), rows 0..2, analytic affine inverses.
// Bottom row of P is exactly [0,0,0,1]. Validated: absmax 0.0 vs reference.
__device__ __forceinline__ void computeQ(const float* __restrict__ K,
                                         const float* __restrict__ RT,
                                         int b, int i, float Q[Vn][12]) {
    const float* Kb = K + (size_t)b * 16;
    const float f  = Kb[0], cx = Kb[2], cy = Kb[6];
    const float rf = 1.0f / f;
    const float* Ti = RT + (size_t)(b * Vn + i) * 16;
    const float A00=Ti[0], A01=Ti[1], A02=Ti[2],  A03=Ti[3];
    const float A10=Ti[4], A11=Ti[5], A12=Ti[6],  A13=Ti[7];
    const float A20=Ti[8], A21=Ti[9], A22=Ti[10], A23=Ti[11];
    const float I00=A00, I01=A10, I02=A20, I03=-(A00*A03 + A10*A13 + A20*A23);
    const float I10=A01, I11=A11, I12=A21, I13=-(A01*A03 + A11*A13 + A21*A23);
    const float I20=A02, I21=A12, I22=A22, I23=-(A02*A03 + A12*A13 + A22*A23);
    #pragma unroll
    for (int j = 0; j < Vn; ++j) {
        const float* Tj = RT + (size_t)(b * Vn + j) * 16;
        const float B00=Tj[0], B01=Tj[1], B02=Tj[2],  B03=Tj[3];
        const float B10=Tj[4], B11=Tj[5], B12=Tj[6],  B13=Tj[7];
        const float B20=Tj[8], B21=Tj[9], B22=Tj[10], B23=Tj[11];
        const float M00=B00*I00+B01*I10+B02*I20, M01=B00*I01+B01*I11+B02*I21,
                    M02=B00*I02+B01*I12+B02*I22, M03=B00*I03+B01*I13+B02*I23+B03;
        const float M10=B10*I00+B11*I10+B12*I20, M11=B10*I01+B11*I11+B12*I21,
                    M12=B10*I02+B11*I12+B12*I22, M13=B10*I03+B11*I13+B12*I23+B13;
        const float M20=B20*I00+B21*I10+B22*I20, M21=B20*I01+B21*I11+B22*I21,
                    M22=B20*I02+B21*I12+B22*I22, M23=B20*I03+B21*I13+B22*I23+B23;
        const float G00=f*M00+cx*M20, G01=f*M01+cx*M21, G02=f*M02+cx*M22, G03=f*M03+cx*M23;
        const float G10=f*M10+cy*M20, G11=f*M11+cy*M21, G12=f*M12+cy*M22, G13=f*M13+cy*M23;
        const float G20=M20,          G21=M21,          G22=M22,          G23=M23;
        Q[j][0]  = rfl(G00*rf);  Q[j][1]  = rfl(G01*rf);
        Q[j][2]  = rfl(G02 - (cx*rf)*G00 - (cy*rf)*G01);  Q[j][3]  = rfl(G03);
        Q[j][4]  = rfl(G10*rf);  Q[j][5]  = rfl(G11*rf);
        Q[j][6]  = rfl(G12 - (cx*rf)*G10 - (cy*rf)*G11);  Q[j][7]  = rfl(G13);
        Q[j][8]  = rfl(G20*rf);  Q[j][9]  = rfl(G21*rf);
        Q[j][10] = rfl(G22 - (cx*rf)*G20 - (cy*rf)*G21);  Q[j][11] = rfl(G23);
    }
}

// ---------- Main: R1 body (proven 43us), fast-path gathers from fp16 J16 ----------
// Structure identical to R1 (best: 110.6us total): exec-masked gathers, ballot
// border fast-path, per-j ascending-k accumulation. Only change: interior
// samples load the 2x2 quad as ONE 8B h2q from J16 (2 dw-lanes/sample, was 4).
// Border path (rare) keeps exact fp32 loads from pred.
__global__ __launch_bounds__(TPB, 8) void loss_main_kernel(const float* __restrict__ pred,
                                                           const __half2* __restrict__ J16,
                                                           const float* __restrict__ K,
                                                           const float* __restrict__ RT,
                                                           float* __restrict__ part) {
    // b = blockIdx.x % 8: XCD-batch L2 locality.
    const int id   = blockIdx.x;
    const int b    = id & 7;
    const int r    = id >> 3;
    const int i    = r % Vn;
    const int xblk = r / Vn;           // 0..79

    float Q[Vn][12];
    computeQ(K, RT, b, i, Q);

    // R20 balance bijection over the 512x40 segment grid (kept):
    const int tid  = threadIdx.x;
    const int h    = (xblk >= 40) ? 1 : 0;
    const int c0   = xblk - 40 * h;
    const int yrow = 2 * tid + h;
    int c = c0 + tid;
    c -= (c / 40) * 40;
    const int xcol = c << 4;
    const int base = yrow * Wn + xcol;
    const float fy = (float)yrow;

    const float* dptr = pred + (size_t)(b * Vn + i) * Nn + base;
    float dv[PX];
    {
        const float4 a0 = *reinterpret_cast<const float4*>(dptr);
        const float4 a1 = *reinterpret_cast<const float4*>(dptr + 4);
        const float4 a2 = *reinterpret_cast<const float4*>(dptr + 8);
        const float4 a3 = *reinterpret_cast<const float4*>(dptr + 12);
        dv[0]=a0.x; dv[1]=a0.y; dv[2]=a0.z; dv[3]=a0.w;
        dv[4]=a1.x; dv[5]=a1.y; dv[6]=a1.z; dv[7]=a1.w;
        dv[8]=a2.x; dv[9]=a2.y; dv[10]=a2.z; dv[11]=a2.w;
        dv[12]=a3.x; dv[13]=a3.y; dv[14]=a3.z; dv[15]=a3.w;
    }

    const float cW = (float)Wn / (float)(Wn - 1);   // ix = X*cW - 0.5
    const float cH = (float)Hn / (float)(Hn - 1);

    float num[Vn] = {0.0f, 0.0f, 0.0f};
    float den[Vn] = {0.0f, 0.0f, 0.0f};

    #pragma unroll
    for (int j = 0; j < Vn; ++j) {
        const float* __restrict__ img  = pred + (size_t)(b * Vn + j) * Nn;
        const __half2* __restrict__ Jb = J16  + (size_t)(b * Vn + j) * Nn;
        const float rx = fmaf(Q[j][1], fy, Q[j][2]);
        const float ry = fmaf(Q[j][5], fy, Q[j][6]);
        const float rz = fmaf(Q[j][9], fy, Q[j][10]);

        #pragma unroll
        for (int k = 0; k < PX; ++k) {
            const float d  = dv[k];
            const float fx = (float)(xcol + k);

            const float X = fmaf(d, fmaf(Q[j][0], fx, rx), Q[j][3]);
            const float Y = fmaf(d, fmaf(Q[j][4], fx, ry), Q[j][7]);
            const float Z = fmaf(d, fmaf(Q[j][8], fx, rz), Q[j][11]);

            const bool inb = (X >= 0.0f) & (X <= (float)(Wn - 1)) &
                             (Y >= 0.0f) & (Y <= (float)(Hn - 1));
            if (inb) {
                const float ix = fmaf(X, cW, -0.5f);
                const float iy = fmaf(Y, cH, -0.5f);
                const float x0f = floorf(ix);
                const float y0f = floorf(iy);
                const float wx1 = ix - x0f;
                const float wy1 = iy - y0f;
                const float wx0 = 1.0f - wx1;
                const float wy0 = 1.0f - wy1;
                const int x0 = (int)x0f;           // in [-1, W-1]
                const int y0 = (int)y0f;           // in [-1, H-1]
                const bool border = (x0 < 0) | (x0 > Wn - 2) | (y0 < 0) | (y0 > Hn - 2);
                float warped;
                if (__ballot(border) == 0ull) {
                    // FAST PATH (~97%): one 8B load = full 2x2 quad (fp16).
                    // r0 = (I[y0][x0], I[y0+1][x0]); r1 = same at x0+1.
                    const h2q q = *reinterpret_cast<const h2q*>(Jb + (y0 * Wn + x0));
                    const float c00 = __low2float(q.r0);
                    const float c01 = __high2float(q.r0);
                    const float c10 = __low2float(q.r1);
                    const float c11 = __high2float(q.r1);
                    warped = wy0 * fmaf(wx0, c00, wx1 * c10)
                           + wy1 * fmaf(wx0, c01, wx1 * c11);
                } else {
                    // BORDER PATH (rare): exact fp32 from pred, as in R1.
                    const int x1 = x0 + 1;
                    const int y1 = y0 + 1;
                    const int cy0 = max(y0, 0);
                    const int cy1 = min(y1, Hn - 1);
                    const int cx  = min(max(x0, 0), Wn - 2);
                    const bool xlo = (x0 >= 0);
                    const bool xhi = (x0 <= Wn - 2);
                    const fpair q0 = *reinterpret_cast<const fpair*>(img + (cy0 * Wn + cx));
                    const fpair q1 = *reinterpret_cast<const fpair*>(img + (cy1 * Wn + cx));
                    const float c00 = xhi ? q0.a : q0.b;
                    const float c10 = xlo ? q0.b : q0.a;
                    const float c01 = xhi ? q1.a : q1.b;
                    const float c11 = xlo ? q1.b : q1.a;
                    const float wx0v = xlo ? wx0 : 0.0f;
                    const float wx1v = (x1 < Wn) ? wx1 : 0.0f;
                    const float wy0v = (y0 >= 0) ? wy0 : 0.0f;
                    const float wy1v = (y1 < Hn) ? wy1 : 0.0f;
                    warped = wy0v * fmaf(wx0v, c00, wx1v * c10)
                           + wy1v * fmaf(wx0v, c01, wx1v * c11);
                }
                num[j] += fabsf(warped - Z);
                den[j] += 1.0f;
            }
        }
    }

    // wave-64 shuffle reduction over 6 independent accumulators
    #pragma unroll
    for (int off = 32; off > 0; off >>= 1) {
        #pragma unroll
        for (int j = 0; j < Vn; ++j) {
            num[j] += __shfl_down(num[j], off, 64);
            den[j] += __shfl_down(den[j], off, 64);
        }
    }
    __shared__ float s_red[4][2 * Vn];
    const int lane = threadIdx.x & 63;
    const int wid  = threadIdx.x >> 6;
    if (lane == 0) {
        #pragma unroll
        for (int j = 0; j < Vn; ++j) {
            s_red[wid][2 * j + 0] = num[j];
            s_red[wid][2 * j + 1] = den[j];
        }
    }
    __syncthreads();
    if (threadIdx.x < 2 * Vn) {
        const int slot = threadIdx.x;
        const float v = s_red[0][slot] + s_red[1][slot] + s_red[2][slot] + s_red[3][slot];
        part[(size_t)id * 8 + slot] = v;
    }
}

// ---------- Finalize: sum 1920 partials -> 9 pair accums -> total ----------
__global__ __launch_bounds__(TPB) void finalize_kernel(const float* __restrict__ part,
                                                       float* __restrict__ out) {
    float acc[2 * Vn * Vn];   // [pair*2 + comp], pair = i*3+j
    #pragma unroll
    for (int s = 0; s < 2 * Vn * Vn; ++s) acc[s] = 0.0f;

    for (int m = threadIdx.x; m < GRIDN; m += TPB) {
        const int i = (m >> 3) % Vn;
        const float* pp = part + (size_t)m * 8;
        #pragma unroll
        for (int j = 0; j < Vn; ++j) {
            acc[(i * Vn + j) * 2 + 0] += pp[2 * j + 0];
            acc[(i * Vn + j) * 2 + 1] += pp[2 * j + 1];
        }
    }
    #pragma unroll
    for (int off = 32; off > 0; off >>= 1) {
        #pragma unroll
        for (int s = 0; s < 2 * Vn * Vn; ++s)
            acc[s] += __shfl_down(acc[s], off, 64);
    }
    __shared__ float s_fin[4][2 * Vn * Vn];
    const int lane = threadIdx.x & 63;
    const int wid  = threadIdx.x >> 6;
    if (lane == 0) {
        #pragma unroll
        for (int s = 0; s < 2 * Vn * Vn; ++s) s_fin[wid][s] = acc[s];
    }
    __syncthreads();
    if (threadIdx.x == 0) {
        float t = 0.0f;
        #pragma unroll
        for (int pr = 0; pr < Vn * Vn; ++pr) {
            const float nn = s_fin[0][pr*2+0] + s_fin[1][pr*2+0] + s_fin[2][pr*2+0] + s_fin[3][pr*2+0];
            const float dd = s_fin[0][pr*2+1] + s_fin[1][pr*2+1] + s_fin[2][pr*2+1] + s_fin[3][pr*2+1];
            t += nn / fmaxf(dd, 1.0f);
        }
        out[0] = t;
    }
}

extern "C" void kernel_launch(void* const* d_in, const int* in_sizes, int n_in,
                              void* d_out, int out_size, void* d_ws, size_t ws_size,
                              hipStream_t stream) {
    const float* pred = (const float*)d_in[0];   // (B,V,H,W)
    const float* K    = (const float*)d_in[1];   // (B,4,4)
    const float* RT   = (const float*)d_in[2];   // (B,V,4,4)
    float* out = (float*)d_out;

    // ws layout: [0, 31.5 MB): fp16 row-pair image (rebuilt every call; the
    // harness re-poisons ws). [64 MB, +61 KB): per-block partials.
    __half2* J16 = (__half2*)d_ws;
    float*   part = (float*)d_ws + JOFF_PART;

    prepass_kernel<<<PRE_GRID, PRE_TPB, 0, stream>>>(pred, J16);
    loss_main_kernel<<<GRIDN, TPB, 0, stream>>>(pred, J16, K, RT, part);
    finalize_kernel<<<1, TPB, 0, stream>>>(part, out);
}